// Round 17
// baseline (256.799 us; speedup 1.0000x reference)
//
#include <hip/hip_runtime.h>
#include <hip/hip_bf16.h>

#define DEV static __device__ __forceinline__

typedef __attribute__((ext_vector_type(4))) float f32x4;
typedef __attribute__((ext_vector_type(8))) short s16x8;
typedef __attribute__((ext_vector_type(4))) unsigned int u32x4;

constexpr int Bn = 4, Tn = 2048, Dn = 1024, Hn = 8, DH = 128;
constexpr float EPSF = 1e-5f;
// attn scale (1/32) * log2(e): softmax done in exp2 domain
constexpr float QSCALE = 0.0450842200277801f;

DEV unsigned short f2bf(float f) {
    unsigned int u = __float_as_uint(f);
    u += 0x7FFF + ((u >> 16) & 1);   // round-to-nearest-even
    return (unsigned short)(u >> 16);
}

DEV f32x4 mfma16(s16x8 a, s16x8 b, f32x4 c) {
    return __builtin_amdgcn_mfma_f32_16x16x32_bf16(a, b, c, 0, 0, 0);
}

DEV float ex2(float x) {            // v_exp_f32 IS exp2
    float r;
    asm("v_exp_f32 %0, %1" : "=v"(r) : "v"(x));
    return r;
}

DEV unsigned int cvtpk(float lo, float hi) {   // bf16(lo) | bf16(hi)<<16, RNE
    unsigned int r;
    asm("v_cvt_pk_bf16_f32 %0, %1, %2" : "=v"(r) : "v"(lo), "v"(hi));
    return r;
}

typedef __attribute__((address_space(1))) const unsigned int GU32;
typedef __attribute__((address_space(3))) unsigned int LU32;
DEV void gload16(const void* g, void* l) {     // async global->LDS, 16B/lane
    __builtin_amdgcn_global_load_lds((GU32*)g, (LU32*)l, 16, 0, 0);
}

// ---------------- fused weight-convert + layernorm ----------------
__global__ __launch_bounds__(256) void cvtln_kernel(const float* __restrict__ x,
                                                    const float* __restrict__ w,
                                                    const float* __restrict__ b,
                                                    const float* __restrict__ qw,
                                                    const float* __restrict__ kw,
                                                    const float* __restrict__ vw,
                                                    const float* __restrict__ ow,
                                                    unsigned short* __restrict__ xn,
                                                    unsigned short* __restrict__ wb) {
    int bid = blockIdx.x;
    int tid = threadIdx.x;
    if (bid >= 8192) {
        int base = (bid - 8192) * 1024 + tid * 4;
        #pragma unroll
        for (int j = 0; j < 4; j++) {
            int idx = base + j;
            int sel = idx >> 20;
            int off = idx & (Dn * Dn - 1);
            const float* src = sel == 0 ? qw : sel == 1 ? kw : sel == 2 ? vw : ow;
            wb[idx] = f2bf(src[off]);
        }
        return;
    }
    int tok = bid;
    const float* xp = x + (size_t)tok * Dn;
    float4 v = ((const float4*)xp)[tid];
    float s = v.x + v.y + v.z + v.w;
    float q = v.x * v.x + v.y * v.y + v.z * v.z + v.w * v.w;
    for (int off = 32; off; off >>= 1) {
        s += __shfl_xor(s, off);
        q += __shfl_xor(q, off);
    }
    __shared__ float red[8];
    __shared__ float stats[2];
    int wid = tid >> 6, lane = tid & 63;
    if (lane == 0) { red[wid] = s; red[4 + wid] = q; }
    __syncthreads();
    if (tid == 0) {
        float ts = red[0] + red[1] + red[2] + red[3];
        float tq = red[4] + red[5] + red[6] + red[7];
        float mu = ts / Dn;
        float var = tq / Dn - mu * mu;
        stats[0] = mu;
        stats[1] = rsqrtf(var + EPSF);
    }
    __syncthreads();
    float mu = stats[0], rs = stats[1];
    int c = tid * 4;
    ushort4 o;
    o.x = f2bf((v.x - mu) * rs * w[c + 0] + b[c + 0]);
    o.y = f2bf((v.y - mu) * rs * w[c + 1] + b[c + 1]);
    o.z = f2bf((v.z - mu) * rs * w[c + 2] + b[c + 2]);
    o.w = f2bf((v.w - mu) * rs * w[c + 3] + b[c + 3]);
    ((ushort4*)(xn + (size_t)tok * Dn))[tid] = o;
}

// ---------------- QKV projection: 128x128, 3-buf depth-2 counted-vmcnt ------
// V written TRANSPOSED+key-permuted: within each 32-t group keys stored at
// position ((t>>2)&3)*8 + ((t>>4)&1)*4 + (t&3) so attention's PV B-fragment
// (local-P k-mapping) is one contiguous 16B load.
__global__ __launch_bounds__(256) void qkv_gemm(const unsigned short* __restrict__ xn,
                                                const unsigned short* __restrict__ wmat,
                                                const float* __restrict__ qb_,
                                                const float* __restrict__ kb_,
                                                const float* __restrict__ vb_,
                                                unsigned short* __restrict__ outq,
                                                unsigned short* __restrict__ outk,
                                                unsigned short* __restrict__ vt) {
    int rowbase = blockIdx.x * 128;
    int colbase = blockIdx.y * 128;
    int matid = blockIdx.z;
    const unsigned short* W = wmat + (size_t)matid * Dn * Dn;
    const float* bias = matid == 0 ? qb_ : matid == 1 ? kb_ : vb_;
    float oscale = matid == 0 ? QSCALE : 1.0f;     // fold attn scale * log2e into Q
    int e = (rowbase & (Tn - 1)) >> 9;             // chunk within T
    int m = Dn >> e;
    int nt = m >> 5;

    __shared__ alignas(16) unsigned short At[3][128 * 32];
    __shared__ alignas(16) unsigned short Bt[3][128 * 32];

    int tid = threadIdx.x;
    int lane = tid & 63, wv = tid >> 6;
    int wr = (wv >> 1) * 64, wc = (wv & 1) * 64;
    int fr = lane & 15, fg = lane >> 4;
    int srow = tid >> 2, scol = (tid & 3) * 8;
    const unsigned short* ga0 = xn + (size_t)(rowbase + srow) * Dn + scol;
    const unsigned short* ga1 = xn + (size_t)(rowbase + 64 + srow) * Dn + scol;
    const unsigned short* gb0 = W + (size_t)(colbase + srow) * Dn + scol;
    const unsigned short* gb1 = W + (size_t)(colbase + 64 + srow) * Dn + scol;

    f32x4 acc[4][4] = {};

    auto STAGE = [&](int tt, int buf) {
        int kk = tt * 32;
        gload16(ga0 + kk, &At[buf][tid * 8]);
        gload16(ga1 + kk, &At[buf][2048 + tid * 8]);
        gload16(gb0 + kk, &Bt[buf][tid * 8]);
        gload16(gb1 + kk, &Bt[buf][2048 + tid * 8]);
    };

    STAGE(0, 0);
    if (nt > 1) STAGE(1, 1);

    int cur = 0, nxt2 = 2;   // buffer indices mod 3 for t and t+2
    for (int t = 0; t < nt; t++) {
        if (t + 1 < nt) { asm volatile("s_waitcnt vmcnt(4)" ::: "memory"); }
        else            { asm volatile("s_waitcnt vmcnt(0)" ::: "memory"); }
        __builtin_amdgcn_s_barrier();
        if (t + 2 < nt) STAGE(t + 2, nxt2);
        s16x8 a[4], b[4];
        #pragma unroll
        for (int i = 0; i < 4; i++) a[i] = *(const s16x8*)&At[cur][(wr + i * 16 + fr) * 32 + fg * 8];
        #pragma unroll
        for (int j = 0; j < 4; j++) b[j] = *(const s16x8*)&Bt[cur][(wc + j * 16 + fr) * 32 + fg * 8];
        #pragma unroll
        for (int i = 0; i < 4; i++)
            #pragma unroll
            for (int j = 0; j < 4; j++) acc[i][j] = mfma16(a[i], b[j], acc[i][j]);
        cur = cur == 2 ? 0 : cur + 1;
        nxt2 = nxt2 == 2 ? 0 : nxt2 + 1;
    }

    if (matid == 2) {
        // V: write transposed+key-permuted vt[((b*H + h)*DH + dh)*Tn + t']
        #pragma unroll
        for (int i = 0; i < 4; i++)
            #pragma unroll
            for (int j = 0; j < 4; j++) {
                int col = colbase + wc + j * 16 + fr;
                float bv = bias[col];
                int row0 = rowbase + wr + i * 16 + fg * 4;
                int bb = row0 >> 11, tl = row0 & (Tn - 1);
                int w32 = tl & 31;
                int tlp = (tl & ~31) | (((w32 >> 2) & 3) * 8 + ((w32 >> 4) & 1) * 4);
                size_t base = (((size_t)bb * Hn + (col >> 7)) * DH + (col & (DH - 1))) * Tn + tlp;
                ushort4 o;
                o.x = f2bf(acc[i][j][0] + bv);
                o.y = f2bf(acc[i][j][1] + bv);
                o.z = f2bf(acc[i][j][2] + bv);
                o.w = f2bf(acc[i][j][3] + bv);
                *(ushort4*)&vt[base] = o;
            }
    } else {
        unsigned short* out = matid == 0 ? outq : outk;
        #pragma unroll
        for (int i = 0; i < 4; i++)
            #pragma unroll
            for (int j = 0; j < 4; j++) {
                int col = colbase + wc + j * 16 + fr;
                float bv = bias[col];
                #pragma unroll
                for (int r = 0; r < 4; r++) {
                    int row = rowbase + wr + i * 16 + fg * 4 + r;
                    out[(size_t)row * Dn + col] = f2bf((acc[i][j][r] + bv) * oscale);
                }
            }
    }
}

// ---------------- flash attention: r8 skeleton + V DIRECT FROM L1/L2 --------
// grid 512 flat (bh = f&31 -> XCD-clustered, K/V L2-resident); 256 thr;
// 4 waves x 32q, KVBLK=64; K in LDS (32KB dbuf, XOR swizzle); V fragments
// loaded DIRECTLY from global (key-permuted vt -> one 16B load per frag,
// fg lanes contiguous 64B/row; 64-key V tile = 16KB fits L1). V loads
// issued right after QKT so L2 latency hides under softmax (T14).
// DS ops/wave/iter: 32+8 -> 16+4 (floor ~41 -> ~22 us); V on TA pipe.
// P in registers, l via ones-column, defer-max, setprio.
__global__ __launch_bounds__(256, 2) void attn_kernel(const unsigned short* __restrict__ Q,
                                                      const unsigned short* __restrict__ K,
                                                      const unsigned short* __restrict__ VT,
                                                      unsigned short* __restrict__ AO) {
    int f = blockIdx.x;
    int qi = f >> 5;               // 0..15  (q-tile of 128)
    int bh = f & 31;               // XCD = f&7
    int b = bh >> 3, h = bh & 7;
    int qbase = qi * 128;
    int tid = threadIdx.x;
    int wv = tid >> 6, lane = tid & 63;
    int fr = lane & 15, fg = lane >> 4;

    __shared__ alignas(16) unsigned short Kt[2][64 * 128];   // [key][d], swizzled chunks

    // Q fragments for both q-halves (B-operand: Q^T[d][q=fr])
    s16x8 bq[2][4];
    #pragma unroll
    for (int hh = 0; hh < 2; hh++) {
        const size_t qr = ((size_t)b * Tn + qbase + wv * 32 + hh * 16 + fr) * Dn + h * DH;
        #pragma unroll
        for (int c = 0; c < 4; c++) bq[hh][c] = *(const s16x8*)&Q[qr + c * 32 + fg * 8];
    }

    const s16x8 ones = {(short)0x3F80, (short)0x3F80, (short)0x3F80, (short)0x3F80,
                        (short)0x3F80, (short)0x3F80, (short)0x3F80, (short)0x3F80};

    f32x4 acc[2][9] = {};          // [hh][0..7]=O d-blocks, [hh][8]=l (ones column)
    float m_run[2] = {-1e30f, -1e30f};

    const unsigned short* Kbase = K + (size_t)b * Tn * Dn + h * DH;
    const unsigned short* Vbase = VT + ((size_t)b * Hn + h) * DH * Tn;
    // per-lane V fragment base: row = n*16+fr, col offset fg*8 (key-permuted)
    const unsigned short* Vlane = Vbase + (size_t)fr * Tn + fg * 8;

    // K staging geometry (256 threads, 16B each, 4 rounds)
    int k_row_lo = tid >> 4, k_chk = tid & 15;   // 16 chunks per 128-d row

    auto STAGE = [&](int t, int buf) {
        int kb = t * 64;
        #pragma unroll
        for (int p = 0; p < 4; p++) {
            int row = p * 16 + k_row_lo;                 // key row 0..63
            int chunk = k_chk ^ (row & 7);
            gload16(Kbase + (size_t)(kb + row) * Dn + chunk * 8,
                    &Kt[buf][p * 2048 + tid * 8]);
        }
    };

    STAGE(0, 0);
    __syncthreads();

    constexpr int NT = Tn / 64;    // 32 iterations
    for (int t = 0; t < NT; t++) {
        int cur = t & 1;
        if (t < NT - 1) STAGE(t + 1, cur ^ 1);
        int kb = t * 64;

        const unsigned short* KtC = &Kt[cur][0];

        // S^T = K Q^T : lane q = fr, key = kt*16 + fg*4 + r
        f32x4 s[2][4] = {};
        __builtin_amdgcn_s_setprio(1);
        #pragma unroll
        for (int c = 0; c < 4; c++) {
            #pragma unroll
            for (int kt = 0; kt < 4; kt++) {
                s16x8 ak = *(const s16x8*)&KtC[(kt * 16 + fr) * 128 +
                                               (((c * 4 + fg) ^ (fr & 7)) * 8)];
                s[0][kt] = mfma16(ak, bq[0][c], s[0][kt]);
                s[1][kt] = mfma16(ak, bq[1][c], s[1][kt]);
            }
        }
        __builtin_amdgcn_s_setprio(0);

        // issue V fragment loads NOW: L2 latency hides under softmax below.
        // frag (ks,n): V[d = n*16+fr][keys kb + ks*32 + fg*8 .. +7] (permuted)
        s16x8 bv[2][8];
        #pragma unroll
        for (int ks = 0; ks < 2; ks++)
            #pragma unroll
            for (int n = 0; n < 8; n++)
                bv[ks][n] = *(const s16x8*)(Vlane + (size_t)(n * 16) * Tn + kb + ks * 32);

        // in-register online max per half (exp2 domain)
        float mx[2];
        #pragma unroll
        for (int hh = 0; hh < 2; hh++) {
            float v = s[hh][0][0];
            #pragma unroll
            for (int kt = 0; kt < 4; kt++)
                #pragma unroll
                for (int r = 0; r < 4; r++) v = fmaxf(v, s[hh][kt][r]);
            v = fmaxf(v, __shfl_xor(v, 16));
            v = fmaxf(v, __shfl_xor(v, 32));
            mx[hh] = v;
        }

        if (!__all(mx[0] - m_run[0] <= 8.0f && mx[1] - m_run[1] <= 8.0f)) {  // T13
            #pragma unroll
            for (int hh = 0; hh < 2; hh++) {
                float mnew = fmaxf(m_run[hh], mx[hh]);
                float fsc = ex2(m_run[hh] - mnew);
                float fw[4];
                #pragma unroll
                for (int r = 0; r < 4; r++) fw[r] = __shfl(fsc, fg * 4 + r);
                #pragma unroll
                for (int n = 0; n < 9; n++)          // includes l column
                    #pragma unroll
                    for (int r = 0; r < 4; r++) acc[hh][n][r] *= fw[r];
                m_run[hh] = mnew;
            }
        }

        // P = exp2(S - m); pa[ks] packed locally: reg j <-> key ks*32+(j>>2)*16+fg*4+(j&3)
        s16x8 pa[2][2];
        #pragma unroll
        for (int hh = 0; hh < 2; hh++) {
            float p[16];
            #pragma unroll
            for (int kt = 0; kt < 4; kt++)
                #pragma unroll
                for (int r = 0; r < 4; r++) p[kt * 4 + r] = ex2(s[hh][kt][r] - m_run[hh]);
            #pragma unroll
            for (int ks = 0; ks < 2; ks++) {
                u32x4 pw;
                pw.x = cvtpk(p[ks * 8 + 0], p[ks * 8 + 1]);
                pw.y = cvtpk(p[ks * 8 + 2], p[ks * 8 + 3]);
                pw.z = cvtpk(p[ks * 8 + 4], p[ks * 8 + 5]);
                pw.w = cvtpk(p[ks * 8 + 6], p[ks * 8 + 7]);
                pa[hh][ks] = __builtin_bit_cast(s16x8, pw);
            }
        }

        // O += P V (+ l column): V fragments already in registers
        __builtin_amdgcn_s_setprio(1);
        #pragma unroll
        for (int ks = 0; ks < 2; ks++) {
            #pragma unroll
            for (int n = 0; n < 8; n++) {
                acc[0][n] = mfma16(pa[0][ks], bv[ks][n], acc[0][n]);
                acc[1][n] = mfma16(pa[1][ks], bv[ks][n], acc[1][n]);
            }
            acc[0][8] = mfma16(pa[0][ks], ones, acc[0][8]);
            acc[1][8] = mfma16(pa[1][ks], ones, acc[1][8]);
        }
        __builtin_amdgcn_s_setprio(0);
        __syncthreads();   // drains vmcnt (STAGE t+1) + protects K buffers
    }

    #pragma unroll
    for (int hh = 0; hh < 2; hh++) {
        float rl[4];
        #pragma unroll
        for (int r = 0; r < 4; r++) rl[r] = 1.0f / acc[hh][8][r];   // l, no shuffle
        size_t orow0 = ((size_t)b * Tn + qbase + wv * 32 + hh * 16) * Dn + h * DH;
        for (int n = 0; n < 8; n++)
            for (int r = 0; r < 4; r++) {
                float v = acc[hh][n][r] * rl[r];
                AO[orow0 + (size_t)(fg * 4 + r) * Dn + n * 16 + fr] = f2bf(v);
            }
    }
}

// ---------------- O projection + pad + residual, 3-buf depth-2 --------------
__global__ __launch_bounds__(256) void oproj_gemm(const unsigned short* __restrict__ A,
                                                  const unsigned short* __restrict__ W,
                                                  const float* __restrict__ bias,
                                                  const float* __restrict__ x,
                                                  float* __restrict__ out) {
    int rowbase = blockIdx.x * 128;
    int colbase = blockIdx.y * 128;
    int e = (rowbase & (Tn - 1)) >> 9;
    int m = Dn >> e;
    int tid = threadIdx.x;

    if (colbase >= m) {   // pad region: pure residual copy (128x128 f32)
        #pragma unroll
        for (int i = 0; i < 16; i++) {
            int idx = i * 256 + tid;
            int r = idx >> 5, c4 = (idx & 31) * 4;
            size_t g = (size_t)(rowbase + r) * Dn + colbase + c4;
            *(float4*)&out[g] = *(const float4*)&x[g];
        }
        return;
    }

    __shared__ alignas(16) unsigned short At[3][128 * 32];
    __shared__ alignas(16) unsigned short Bt[3][128 * 32];
    int lane = tid & 63, wv = tid >> 6;
    int wr = (wv >> 1) * 64, wc = (wv & 1) * 64;
    int fr = lane & 15, fg = lane >> 4;
    int srow = tid >> 2, scol = (tid & 3) * 8;
    const unsigned short* ga0 = A + (size_t)(rowbase + srow) * Dn + scol;
    const unsigned short* ga1 = A + (size_t)(rowbase + 64 + srow) * Dn + scol;
    const unsigned short* gb0 = W + (size_t)(colbase + srow) * Dn + scol;
    const unsigned short* gb1 = W + (size_t)(colbase + 64 + srow) * Dn + scol;
    int nt = m >> 5;

    f32x4 acc[4][4] = {};

    auto STAGE = [&](int tt, int buf) {
        int kk = tt * 32;
        gload16(ga0 + kk, &At[buf][tid * 8]);
        gload16(ga1 + kk, &At[buf][2048 + tid * 8]);
        gload16(gb0 + kk, &Bt[buf][tid * 8]);
        gload16(gb1 + kk, &Bt[buf][2048 + tid * 8]);
    };

    STAGE(0, 0);
    if (nt > 1) STAGE(1, 1);

    int cur = 0, nxt2 = 2;
    for (int t = 0; t < nt; t++) {
        if (t + 1 < nt) { asm volatile("s_waitcnt vmcnt(4)" ::: "memory"); }
        else            { asm volatile("s_waitcnt vmcnt(0)" ::: "memory"); }
        __builtin_amdgcn_s_barrier();
        if (t + 2 < nt) STAGE(t + 2, nxt2);
        s16x8 a[4], b[4];
        #pragma unroll
        for (int i = 0; i < 4; i++) a[i] = *(const s16x8*)&At[cur][(wr + i * 16 + fr) * 32 + fg * 8];
        #pragma unroll
        for (int j = 0; j < 4; j++) b[j] = *(const s16x8*)&Bt[cur][(wc + j * 16 + fr) * 32 + fg * 8];
        #pragma unroll
        for (int i = 0; i < 4; i++)
            #pragma unroll
            for (int j = 0; j < 4; j++) acc[i][j] = mfma16(a[i], b[j], acc[i][j]);
        cur = cur == 2 ? 0 : cur + 1;
        nxt2 = nxt2 == 2 ? 0 : nxt2 + 1;
    }

    #pragma unroll
    for (int i = 0; i < 4; i++)
        #pragma unroll
        for (int j = 0; j < 4; j++) {
            int col = colbase + wc + j * 16 + fr;
            float bv = bias[col];
            #pragma unroll
            for (int r = 0; r < 4; r++) {
                int row = rowbase + wr + i * 16 + fg * 4 + r;
                size_t g = (size_t)row * Dn + col;
                out[g] = acc[i][j][r] + bv + x[g];
            }
        }
}

extern "C" void kernel_launch(void* const* d_in, const int* in_sizes, int n_in,
                              void* d_out, int out_size, void* d_ws, size_t ws_size,
                              hipStream_t stream) {
    const float* x   = (const float*)d_in[0];
    const float* nw  = (const float*)d_in[2];
    const float* nb  = (const float*)d_in[3];
    const float* qw  = (const float*)d_in[4];
    const float* qb_ = (const float*)d_in[5];
    const float* kw  = (const float*)d_in[6];
    const float* kb_ = (const float*)d_in[7];
    const float* vw  = (const float*)d_in[8];
    const float* vb_ = (const float*)d_in[9];
    const float* ow  = (const float*)d_in[10];
    const float* ob_ = (const float*)d_in[11];
    float* out = (float*)d_out;

    unsigned short* ws = (unsigned short*)d_ws;
    const size_t NTOK = (size_t)Bn * Tn;        // 8192
    unsigned short* xn = ws;                    // layernorm output, bf16
    unsigned short* qd = xn + NTOK * Dn;
    unsigned short* kd = qd + NTOK * Dn;
    unsigned short* vt = kd + NTOK * Dn;        // V transposed+permuted [B][H][DH][T']
    unsigned short* ao = vt + NTOK * Dn;        // attention output, bf16
    unsigned short* wb = ao + NTOK * Dn;        // [wq|wk|wv|wo] bf16

    hipLaunchKernelGGL(cvtln_kernel, dim3(12288), dim3(256), 0, stream,
                       x, nw, nb, qw, kw, vw, ow, xn, wb);
    hipLaunchKernelGGL(qkv_gemm, dim3(64, 8, 3), dim3(256), 0, stream,
                       xn, wb, qb_, kb_, vb_, qd, kd, vt);
    hipLaunchKernelGGL(attn_kernel, dim3(512), dim3(256), 0, stream, qd, kd, vt, ao);
    hipLaunchKernelGGL(oproj_gemm, dim3(64, 8), dim3(256), 0, stream,
                       ao, wb + (size_t)3 * Dn * Dn, ob_, x, out);
}

// Round 18
// 185.280 us; speedup vs baseline: 1.3860x; 1.3860x over previous
//
#include <hip/hip_runtime.h>
#include <hip/hip_bf16.h>

#define DEV static __device__ __forceinline__

typedef __attribute__((ext_vector_type(4))) float f32x4;
typedef __attribute__((ext_vector_type(8))) short s16x8;
typedef __attribute__((ext_vector_type(4))) unsigned int u32x4;

constexpr int Bn = 4, Tn = 2048, Dn = 1024, Hn = 8, DH = 128;
constexpr float EPSF = 1e-5f;
// attn scale (1/32) * log2(e): softmax done in exp2 domain
constexpr float QSCALE = 0.0450842200277801f;

DEV unsigned short f2bf(float f) {
    unsigned int u = __float_as_uint(f);
    u += 0x7FFF + ((u >> 16) & 1);   // round-to-nearest-even
    return (unsigned short)(u >> 16);
}

DEV f32x4 mfma16(s16x8 a, s16x8 b, f32x4 c) {
    return __builtin_amdgcn_mfma_f32_16x16x32_bf16(a, b, c, 0, 0, 0);
}

DEV float ex2(float x) {            // v_exp_f32 IS exp2
    float r;
    asm("v_exp_f32 %0, %1" : "=v"(r) : "v"(x));
    return r;
}

DEV unsigned int cvtpk(float lo, float hi) {   // bf16(lo) | bf16(hi)<<16, RNE
    unsigned int r;
    asm("v_cvt_pk_bf16_f32 %0, %1, %2" : "=v"(r) : "v"(lo), "v"(hi));
    return r;
}

typedef __attribute__((address_space(1))) const unsigned int GU32;
typedef __attribute__((address_space(3))) unsigned int LU32;
DEV void gload16(const void* g, void* l) {     // async global->LDS, 16B/lane
    __builtin_amdgcn_global_load_lds((GU32*)g, (LU32*)l, 16, 0, 0);
}

// ---------------- fused weight-convert + layernorm ----------------
__global__ __launch_bounds__(256) void cvtln_kernel(const float* __restrict__ x,
                                                    const float* __restrict__ w,
                                                    const float* __restrict__ b,
                                                    const float* __restrict__ qw,
                                                    const float* __restrict__ kw,
                                                    const float* __restrict__ vw,
                                                    const float* __restrict__ ow,
                                                    unsigned short* __restrict__ xn,
                                                    unsigned short* __restrict__ wb) {
    int bid = blockIdx.x;
    int tid = threadIdx.x;
    if (bid >= 8192) {
        int base = (bid - 8192) * 1024 + tid * 4;
        #pragma unroll
        for (int j = 0; j < 4; j++) {
            int idx = base + j;
            int sel = idx >> 20;
            int off = idx & (Dn * Dn - 1);
            const float* src = sel == 0 ? qw : sel == 1 ? kw : sel == 2 ? vw : ow;
            wb[idx] = f2bf(src[off]);
        }
        return;
    }
    int tok = bid;
    const float* xp = x + (size_t)tok * Dn;
    float4 v = ((const float4*)xp)[tid];
    float s = v.x + v.y + v.z + v.w;
    float q = v.x * v.x + v.y * v.y + v.z * v.z + v.w * v.w;
    for (int off = 32; off; off >>= 1) {
        s += __shfl_xor(s, off);
        q += __shfl_xor(q, off);
    }
    __shared__ float red[8];
    __shared__ float stats[2];
    int wid = tid >> 6, lane = tid & 63;
    if (lane == 0) { red[wid] = s; red[4 + wid] = q; }
    __syncthreads();
    if (tid == 0) {
        float ts = red[0] + red[1] + red[2] + red[3];
        float tq = red[4] + red[5] + red[6] + red[7];
        float mu = ts / Dn;
        float var = tq / Dn - mu * mu;
        stats[0] = mu;
        stats[1] = rsqrtf(var + EPSF);
    }
    __syncthreads();
    float mu = stats[0], rs = stats[1];
    int c = tid * 4;
    ushort4 o;
    o.x = f2bf((v.x - mu) * rs * w[c + 0] + b[c + 0]);
    o.y = f2bf((v.y - mu) * rs * w[c + 1] + b[c + 1]);
    o.z = f2bf((v.z - mu) * rs * w[c + 2] + b[c + 2]);
    o.w = f2bf((v.w - mu) * rs * w[c + 3] + b[c + 3]);
    ((ushort4*)(xn + (size_t)tok * Dn))[tid] = o;
}

// ---------------- QKV projection: 128x128, 3-buf depth-2 counted-vmcnt ------
// V written TRANSPOSED+key-permuted: within each 32-t group keys stored at
// position ((t>>2)&3)*8 + ((t>>4)&1)*4 + (t&3) so attention's PV B-fragment
// (local-P k-mapping) is one contiguous b128.
__global__ __launch_bounds__(256) void qkv_gemm(const unsigned short* __restrict__ xn,
                                                const unsigned short* __restrict__ wmat,
                                                const float* __restrict__ qb_,
                                                const float* __restrict__ kb_,
                                                const float* __restrict__ vb_,
                                                unsigned short* __restrict__ outq,
                                                unsigned short* __restrict__ outk,
                                                unsigned short* __restrict__ vt) {
    int rowbase = blockIdx.x * 128;
    int colbase = blockIdx.y * 128;
    int matid = blockIdx.z;
    const unsigned short* W = wmat + (size_t)matid * Dn * Dn;
    const float* bias = matid == 0 ? qb_ : matid == 1 ? kb_ : vb_;
    float oscale = matid == 0 ? QSCALE : 1.0f;     // fold attn scale * log2e into Q
    int e = (rowbase & (Tn - 1)) >> 9;             // chunk within T
    int m = Dn >> e;
    int nt = m >> 5;

    __shared__ alignas(16) unsigned short At[3][128 * 32];
    __shared__ alignas(16) unsigned short Bt[3][128 * 32];

    int tid = threadIdx.x;
    int lane = tid & 63, wv = tid >> 6;
    int wr = (wv >> 1) * 64, wc = (wv & 1) * 64;
    int fr = lane & 15, fg = lane >> 4;
    int srow = tid >> 2, scol = (tid & 3) * 8;
    const unsigned short* ga0 = xn + (size_t)(rowbase + srow) * Dn + scol;
    const unsigned short* ga1 = xn + (size_t)(rowbase + 64 + srow) * Dn + scol;
    const unsigned short* gb0 = W + (size_t)(colbase + srow) * Dn + scol;
    const unsigned short* gb1 = W + (size_t)(colbase + 64 + srow) * Dn + scol;

    f32x4 acc[4][4] = {};

    auto STAGE = [&](int tt, int buf) {
        int kk = tt * 32;
        gload16(ga0 + kk, &At[buf][tid * 8]);
        gload16(ga1 + kk, &At[buf][2048 + tid * 8]);
        gload16(gb0 + kk, &Bt[buf][tid * 8]);
        gload16(gb1 + kk, &Bt[buf][2048 + tid * 8]);
    };

    STAGE(0, 0);
    if (nt > 1) STAGE(1, 1);

    int cur = 0, nxt2 = 2;   // buffer indices mod 3 for t and t+2
    for (int t = 0; t < nt; t++) {
        if (t + 1 < nt) { asm volatile("s_waitcnt vmcnt(4)" ::: "memory"); }
        else            { asm volatile("s_waitcnt vmcnt(0)" ::: "memory"); }
        __builtin_amdgcn_s_barrier();
        if (t + 2 < nt) STAGE(t + 2, nxt2);
        s16x8 a[4], b[4];
        #pragma unroll
        for (int i = 0; i < 4; i++) a[i] = *(const s16x8*)&At[cur][(wr + i * 16 + fr) * 32 + fg * 8];
        #pragma unroll
        for (int j = 0; j < 4; j++) b[j] = *(const s16x8*)&Bt[cur][(wc + j * 16 + fr) * 32 + fg * 8];
        #pragma unroll
        for (int i = 0; i < 4; i++)
            #pragma unroll
            for (int j = 0; j < 4; j++) acc[i][j] = mfma16(a[i], b[j], acc[i][j]);
        cur = cur == 2 ? 0 : cur + 1;
        nxt2 = nxt2 == 2 ? 0 : nxt2 + 1;
    }

    if (matid == 2) {
        // V: write transposed+key-permuted vt[((b*H + h)*DH + dh)*Tn + t']
        #pragma unroll
        for (int i = 0; i < 4; i++)
            #pragma unroll
            for (int j = 0; j < 4; j++) {
                int col = colbase + wc + j * 16 + fr;
                float bv = bias[col];
                int row0 = rowbase + wr + i * 16 + fg * 4;
                int bb = row0 >> 11, tl = row0 & (Tn - 1);
                int w32 = tl & 31;
                int tlp = (tl & ~31) | (((w32 >> 2) & 3) * 8 + ((w32 >> 4) & 1) * 4);
                size_t base = (((size_t)bb * Hn + (col >> 7)) * DH + (col & (DH - 1))) * Tn + tlp;
                ushort4 o;
                o.x = f2bf(acc[i][j][0] + bv);
                o.y = f2bf(acc[i][j][1] + bv);
                o.z = f2bf(acc[i][j][2] + bv);
                o.w = f2bf(acc[i][j][3] + bv);
                *(ushort4*)&vt[base] = o;
            }
    } else {
        unsigned short* out = matid == 0 ? outq : outk;
        #pragma unroll
        for (int i = 0; i < 4; i++)
            #pragma unroll
            for (int j = 0; j < 4; j++) {
                int col = colbase + wc + j * 16 + fr;
                float bv = bias[col];
                #pragma unroll
                for (int r = 0; r < 4; r++) {
                    int row = rowbase + wr + i * 16 + fg * 4 + r;
                    out[(size_t)row * Dn + col] = f2bf((acc[i][j][r] + bv) * oscale);
                }
            }
    }
}

// ---------------- flash attention: 8 waves x 32q, KVBLK=128, dbuf -----------
// grid 256 flat (bh = f&31 -> XCD-clustered); 512 thr; 128KB LDS; 1 block/CU
// = 8 waves/CU = 2/SIMD with 16 barrier rounds. Best-measured configuration
// (r14: attn 81.7us). P in registers (cvt_pk), l via ones-column, defer-max,
// setprio, key-permuted V -> one b128 per PV B-fragment, XOR swizzles.
__global__ __launch_bounds__(512, 1) void attn_kernel(const unsigned short* __restrict__ Q,
                                                      const unsigned short* __restrict__ K,
                                                      const unsigned short* __restrict__ VT,
                                                      unsigned short* __restrict__ AO) {
    int f = blockIdx.x;
    int qi = f >> 5;               // 0..7  (q-tile of 256)
    int bh = f & 31;               // XCD = f&7
    int b = bh >> 3, h = bh & 7;
    int qbase = qi * 256;
    int tid = threadIdx.x;         // 0..511
    int wv = tid >> 6, lane = tid & 63;
    int fr = lane & 15, fg = lane >> 4;

    __shared__ alignas(16) unsigned short Kt[2][128 * 128];  // [key][d], swizzled chunks
    __shared__ alignas(16) unsigned short Vt[2][128 * 128];  // [d][pos'], swizzled chunks

    // Q fragments for both q-halves (B-operand: Q^T[d][q=fr]); wave wv owns q 32*wv..
    s16x8 bq[2][4];
    #pragma unroll
    for (int hh = 0; hh < 2; hh++) {
        const size_t qr = ((size_t)b * Tn + qbase + wv * 32 + hh * 16 + fr) * Dn + h * DH;
        #pragma unroll
        for (int c = 0; c < 4; c++) bq[hh][c] = *(const s16x8*)&Q[qr + c * 32 + fg * 8];
    }

    const s16x8 ones = {(short)0x3F80, (short)0x3F80, (short)0x3F80, (short)0x3F80,
                        (short)0x3F80, (short)0x3F80, (short)0x3F80, (short)0x3F80};

    f32x4 acc[2][9] = {};          // [hh][0..7]=O d-blocks, [hh][8]=l (ones column)
    float m_run[2] = {-1e30f, -1e30f};

    const unsigned short* Kbase = K + (size_t)b * Tn * Dn + h * DH;
    const unsigned short* Vbase = VT + ((size_t)b * Hn + h) * DH * Tn;

    // staging (512 threads, 16B each, 4 rounds per matrix)
    int s_row_lo = tid >> 4, s_chk = tid & 15;   // 16 chunks per 128-elem row

    auto STAGE = [&](int t, int buf) {
        int kb = t * 128;
        #pragma unroll
        for (int p = 0; p < 4; p++) {
            int row = p * 32 + s_row_lo;                 // key row 0..127
            int chunk = s_chk ^ (row & 7);               // K read XORs fr&7 only
            gload16(Kbase + (size_t)(kb + row) * Dn + chunk * 8,
                    &Kt[buf][p * 4096 + tid * 8]);
        }
        #pragma unroll
        for (int p = 0; p < 4; p++) {
            int row = p * 32 + s_row_lo;                 // d row 0..127
            int chunk = s_chk ^ (row & 15);              // V read XORs fr (4 bits)
            gload16(Vbase + (size_t)row * Tn + kb + chunk * 8,
                    &Vt[buf][p * 4096 + tid * 8]);
        }
    };

    STAGE(0, 0);
    __syncthreads();

    constexpr int NT = Tn / 128;   // 16 iterations
    for (int t = 0; t < NT; t++) {
        int cur = t & 1;
        if (t < NT - 1) STAGE(t + 1, cur ^ 1);

        const unsigned short* KtC = &Kt[cur][0];
        const unsigned short* VtC = &Vt[cur][0];

        // S^T = K Q^T : lane q = fr, key = kt*16 + fg*4 + r (kt = 0..7)
        f32x4 s[2][8] = {};
        __builtin_amdgcn_s_setprio(1);
        #pragma unroll
        for (int c = 0; c < 4; c++) {
            #pragma unroll
            for (int kt = 0; kt < 8; kt++) {
                s16x8 ak = *(const s16x8*)&KtC[(kt * 16 + fr) * 128 +
                                               (((c * 4 + fg) ^ (fr & 7)) * 8)];
                s[0][kt] = mfma16(ak, bq[0][c], s[0][kt]);
                s[1][kt] = mfma16(ak, bq[1][c], s[1][kt]);
            }
        }
        __builtin_amdgcn_s_setprio(0);

        // in-register online max per half (exp2 domain)
        float mx[2];
        #pragma unroll
        for (int hh = 0; hh < 2; hh++) {
            float v = s[hh][0][0];
            #pragma unroll
            for (int kt = 0; kt < 8; kt++)
                #pragma unroll
                for (int r = 0; r < 4; r++) v = fmaxf(v, s[hh][kt][r]);
            v = fmaxf(v, __shfl_xor(v, 16));
            v = fmaxf(v, __shfl_xor(v, 32));
            mx[hh] = v;
        }

        if (!__all(mx[0] - m_run[0] <= 8.0f && mx[1] - m_run[1] <= 8.0f)) {  // T13
            #pragma unroll
            for (int hh = 0; hh < 2; hh++) {
                float mnew = fmaxf(m_run[hh], mx[hh]);
                float fsc = ex2(m_run[hh] - mnew);
                float fw[4];
                #pragma unroll
                for (int r = 0; r < 4; r++) fw[r] = __shfl(fsc, fg * 4 + r);
                #pragma unroll
                for (int n = 0; n < 9; n++)          // includes l column
                    #pragma unroll
                    for (int r = 0; r < 4; r++) acc[hh][n][r] *= fw[r];
                m_run[hh] = mnew;
            }
        }

        // P = exp2(S - m); pa[ks] packed locally (ks = 0..3, 32 keys each):
        // reg j <-> key ks*32 + (j>>2)*16 + fg*4 + (j&3)
        s16x8 pa[2][4];
        #pragma unroll
        for (int hh = 0; hh < 2; hh++) {
            #pragma unroll
            for (int ks = 0; ks < 4; ks++) {
                float p0 = ex2(s[hh][ks * 2 + 0][0] - m_run[hh]);
                float p1 = ex2(s[hh][ks * 2 + 0][1] - m_run[hh]);
                float p2 = ex2(s[hh][ks * 2 + 0][2] - m_run[hh]);
                float p3 = ex2(s[hh][ks * 2 + 0][3] - m_run[hh]);
                float p4 = ex2(s[hh][ks * 2 + 1][0] - m_run[hh]);
                float p5 = ex2(s[hh][ks * 2 + 1][1] - m_run[hh]);
                float p6 = ex2(s[hh][ks * 2 + 1][2] - m_run[hh]);
                float p7 = ex2(s[hh][ks * 2 + 1][3] - m_run[hh]);
                u32x4 pw;
                pw.x = cvtpk(p0, p1);
                pw.y = cvtpk(p2, p3);
                pw.z = cvtpk(p4, p5);
                pw.w = cvtpk(p6, p7);
                pa[hh][ks] = __builtin_bit_cast(s16x8, pw);
            }
        }

        // O += P V (+ l column): one b128 per (ks,n)
        __builtin_amdgcn_s_setprio(1);
        #pragma unroll
        for (int ks = 0; ks < 4; ks++) {
            #pragma unroll
            for (int n = 0; n < 8; n++) {
                int row = n * 16 + fr;
                s16x8 bv = *(const s16x8*)&VtC[row * 128 +
                                               (((ks * 4 + fg) ^ (row & 15)) * 8)];
                acc[0][n] = mfma16(pa[0][ks], bv, acc[0][n]);
                acc[1][n] = mfma16(pa[1][ks], bv, acc[1][n]);
            }
            acc[0][8] = mfma16(pa[0][ks], ones, acc[0][8]);
            acc[1][8] = mfma16(pa[1][ks], ones, acc[1][8]);
        }
        __builtin_amdgcn_s_setprio(0);
        __syncthreads();   // drains vmcnt (STAGE t+1) + protects buffers
    }

    #pragma unroll
    for (int hh = 0; hh < 2; hh++) {
        float rl[4];
        #pragma unroll
        for (int r = 0; r < 4; r++) rl[r] = 1.0f / acc[hh][8][r];   // l, no shuffle
        size_t orow0 = ((size_t)b * Tn + qbase + wv * 32 + hh * 16) * Dn + h * DH;
        for (int n = 0; n < 8; n++)
            for (int r = 0; r < 4; r++) {
                float v = acc[hh][n][r] * rl[r];
                AO[orow0 + (size_t)(fg * 4 + r) * Dn + n * 16 + fr] = f2bf(v);
            }
    }
}

// ---------------- O projection + pad + residual, 3-buf depth-2 --------------
__global__ __launch_bounds__(256) void oproj_gemm(const unsigned short* __restrict__ A,
                                                  const unsigned short* __restrict__ W,
                                                  const float* __restrict__ bias,
                                                  const float* __restrict__ x,
                                                  float* __restrict__ out) {
    int rowbase = blockIdx.x * 128;
    int colbase = blockIdx.y * 128;
    int e = (rowbase & (Tn - 1)) >> 9;
    int m = Dn >> e;
    int tid = threadIdx.x;

    if (colbase >= m) {   // pad region: pure residual copy (128x128 f32)
        #pragma unroll
        for (int i = 0; i < 16; i++) {
            int idx = i * 256 + tid;
            int r = idx >> 5, c4 = (idx & 31) * 4;
            size_t g = (size_t)(rowbase + r) * Dn + colbase + c4;
            *(float4*)&out[g] = *(const float4*)&x[g];
        }
        return;
    }

    __shared__ alignas(16) unsigned short At[3][128 * 32];
    __shared__ alignas(16) unsigned short Bt[3][128 * 32];
    int lane = tid & 63, wv = tid >> 6;
    int wr = (wv >> 1) * 64, wc = (wv & 1) * 64;
    int fr = lane & 15, fg = lane >> 4;
    int srow = tid >> 2, scol = (tid & 3) * 8;
    const unsigned short* ga0 = A + (size_t)(rowbase + srow) * Dn + scol;
    const unsigned short* ga1 = A + (size_t)(rowbase + 64 + srow) * Dn + scol;
    const unsigned short* gb0 = W + (size_t)(colbase + srow) * Dn + scol;
    const unsigned short* gb1 = W + (size_t)(colbase + 64 + srow) * Dn + scol;
    int nt = m >> 5;

    f32x4 acc[4][4] = {};

    auto STAGE = [&](int tt, int buf) {
        int kk = tt * 32;
        gload16(ga0 + kk, &At[buf][tid * 8]);
        gload16(ga1 + kk, &At[buf][2048 + tid * 8]);
        gload16(gb0 + kk, &Bt[buf][tid * 8]);
        gload16(gb1 + kk, &Bt[buf][2048 + tid * 8]);
    };

    STAGE(0, 0);
    if (nt > 1) STAGE(1, 1);

    int cur = 0, nxt2 = 2;
    for (int t = 0; t < nt; t++) {
        if (t + 1 < nt) { asm volatile("s_waitcnt vmcnt(4)" ::: "memory"); }
        else            { asm volatile("s_waitcnt vmcnt(0)" ::: "memory"); }
        __builtin_amdgcn_s_barrier();
        if (t + 2 < nt) STAGE(t + 2, nxt2);
        s16x8 a[4], b[4];
        #pragma unroll
        for (int i = 0; i < 4; i++) a[i] = *(const s16x8*)&At[cur][(wr + i * 16 + fr) * 32 + fg * 8];
        #pragma unroll
        for (int j = 0; j < 4; j++) b[j] = *(const s16x8*)&Bt[cur][(wc + j * 16 + fr) * 32 + fg * 8];
        #pragma unroll
        for (int i = 0; i < 4; i++)
            #pragma unroll
            for (int j = 0; j < 4; j++) acc[i][j] = mfma16(a[i], b[j], acc[i][j]);
        cur = cur == 2 ? 0 : cur + 1;
        nxt2 = nxt2 == 2 ? 0 : nxt2 + 1;
    }

    #pragma unroll
    for (int i = 0; i < 4; i++)
        #pragma unroll
        for (int j = 0; j < 4; j++) {
            int col = colbase + wc + j * 16 + fr;
            float bv = bias[col];
            #pragma unroll
            for (int r = 0; r < 4; r++) {
                int row = rowbase + wr + i * 16 + fg * 4 + r;
                size_t g = (size_t)row * Dn + col;
                out[g] = acc[i][j][r] + bv + x[g];
            }
        }
}

extern "C" void kernel_launch(void* const* d_in, const int* in_sizes, int n_in,
                              void* d_out, int out_size, void* d_ws, size_t ws_size,
                              hipStream_t stream) {
    const float* x   = (const float*)d_in[0];
    const float* nw  = (const float*)d_in[2];
    const float* nb  = (const float*)d_in[3];
    const float* qw  = (const float*)d_in[4];
    const float* qb_ = (const float*)d_in[5];
    const float* kw  = (const float*)d_in[6];
    const float* kb_ = (const float*)d_in[7];
    const float* vw  = (const float*)d_in[8];
    const float* vb_ = (const float*)d_in[9];
    const float* ow  = (const float*)d_in[10];
    const float* ob_ = (const float*)d_in[11];
    float* out = (float*)d_out;

    unsigned short* ws = (unsigned short*)d_ws;
    const size_t NTOK = (size_t)Bn * Tn;        // 8192
    unsigned short* xn = ws;                    // layernorm output, bf16
    unsigned short* qd = xn + NTOK * Dn;
    unsigned short* kd = qd + NTOK * Dn;
    unsigned short* vt = kd + NTOK * Dn;        // V transposed+permuted [B][H][DH][T']
    unsigned short* ao = vt + NTOK * Dn;        // attention output, bf16
    unsigned short* wb = ao + NTOK * Dn;        // [wq|wk|wv|wo] bf16

    hipLaunchKernelGGL(cvtln_kernel, dim3(12288), dim3(256), 0, stream,
                       x, nw, nb, qw, kw, vw, ow, xn, wb);
    hipLaunchKernelGGL(qkv_gemm, dim3(64, 8, 3), dim3(256), 0, stream,
                       xn, wb, qb_, kb_, vb_, qd, kd, vt);
    hipLaunchKernelGGL(attn_kernel, dim3(256), dim3(512), 0, stream, qd, kd, vt, ao);
    hipLaunchKernelGGL(oproj_gemm, dim3(64, 8), dim3(256), 0, stream,
                       ao, wb + (size_t)3 * Dn * Dn, ob_, x, out);
}